// Round 9
// baseline (354.670 us; speedup 1.0000x reference)
//
#include <hip/hip_runtime.h>
#include <cstdint>
#include <cstddef>

#define NEG_SLOPE 0.2f
#define LOG2E 1.44269504f
#define NBLK 256              // CSR sort: blocks in hist/scatter passes

typedef __attribute__((ext_vector_type(8))) short short8;   // 8 bf16 (4 VGPRs)
typedef __attribute__((ext_vector_type(4))) float f32x4;    // MFMA accumulator

__device__ __forceinline__ float bf2f(unsigned short u) {
    union { unsigned int i; float f; } x; x.i = ((unsigned int)u) << 16; return x.f;
}
__device__ __forceinline__ float lo16f(unsigned int u) {
    union { unsigned int i; float f; } x; x.i = u << 16; return x.f;
}
__device__ __forceinline__ float hi16f(unsigned int u) {
    union { unsigned int i; float f; } x; x.i = u & 0xFFFF0000u; return x.f;
}
__device__ __forceinline__ unsigned short f2bf(float f) {
    union { float f; unsigned int i; } x;
    x.f = f;
    unsigned int u = x.i;
    return (unsigned short)((u + 0x7FFFu + ((u >> 16) & 1u)) >> 16);   // RNE
}

// 4-lane (quad-aligned) sum via DPP on the VALU pipe: xor1, xor2.
__device__ __forceinline__ float dpp_sum4(float p) {
    p += __int_as_float(__builtin_amdgcn_update_dpp(0, __float_as_int(p), 0xB1, 0xF, 0xF, true));  // quad_perm [1,0,3,2]
    p += __int_as_float(__builtin_amdgcn_update_dpp(0, __float_as_int(p), 0x4E, 0xF, 0xF, true));  // quad_perm [2,3,0,1]
    return p;
}

// =====================================================================
// FUSED: weight prep (all 3 layers) + CSR coarse histogram (blocks<256).
// Grid = 288 blocks (prep range = 73728 elems). Proven in r6/r8.
// =====================================================================
__global__ __launch_bounds__(256) void prep_and_hist(
    const float* __restrict__ Wl0, const float* __restrict__ Wr0,
    const float* __restrict__ Wl1, const float* __restrict__ Wr1,
    const float* __restrict__ Wl2, const float* __restrict__ Wr2,
    unsigned short* __restrict__ Bt0, unsigned short* __restrict__ Bt1,
    unsigned short* __restrict__ Bt2,
    const int* __restrict__ dst, int E, int tile, int* __restrict__ hist)
{
    __shared__ int h[256];
    const int t = threadIdx.x;
    const int b = blockIdx.x;
    if (b < NBLK) {                       // block-uniform branch: barriers safe
        h[t] = 0;
        __syncthreads();
        const int e0 = b * tile;
        const int e1 = min(E, e0 + tile);
        for (int e = e0 + t; e < e1; e += 256)
            atomicAdd(&h[dst[e] >> 8], 1);
        __syncthreads();
        hist[t * NBLK + b] = h[t];
    }
    // ---- weight prep
    int idx = b * 256 + t;
    const int SZ = 256 * 128;     // layer0/1 table elems
    const float *Wl, *Wr; unsigned short* Bt; int dout;
    if (idx < SZ)              { Wl = Wl0; Wr = Wr0; Bt = Bt0; dout = 128; }
    else if (idx < 2 * SZ)     { Wl = Wl1; Wr = Wr1; Bt = Bt1; dout = 128; idx -= SZ; }
    else if (idx < 2 * SZ + 64 * 128) { Wl = Wl2; Wr = Wr2; Bt = Bt2; dout = 32; idx -= 2 * SZ; }
    else return;
    int n = idx >> 7, k = idx & 127;
    float v = (n < dout) ? Wl[(size_t)k * dout + n] : Wr[(size_t)k * dout + (n - dout)];
    Bt[idx] = f2bf(v);
}

// =====================================================================
// Scan of the 65536-entry histogram in TWO dispatches (r8, frozen).
// =====================================================================
__global__ __launch_bounds__(256) void scan_partial(
    const int* __restrict__ cnt, int Ntot, int* __restrict__ bsum)
{
    __shared__ int red[4];
    const int t = threadIdx.x;
    const int base = blockIdx.x * 2048;
    int s = 0;
#pragma unroll
    for (int i = 0; i < 8; ++i) {
        int idx = base + t + i * 256;
        if (idx < Ntot) s += cnt[idx];
    }
#pragma unroll
    for (int off = 32; off >= 1; off >>= 1) s += __shfl_xor(s, off);
    if ((t & 63) == 0) red[t >> 6] = s;
    __syncthreads();
    if (t == 0) bsum[blockIdx.x] = red[0] + red[1] + red[2] + red[3];
}

__global__ __launch_bounds__(256) void scan_final32(
    const int* __restrict__ cnt, int Ntot, const int* __restrict__ bsum,
    int* __restrict__ outp)
{
    __shared__ int sdat[2048];
    __shared__ int tsum[256];
    const int t = threadIdx.x;
    const int base = blockIdx.x * 2048;
    int bbase = 0;
    for (int i = 0; i < blockIdx.x; ++i) bbase += bsum[i];   // redundant, cached
#pragma unroll
    for (int i = 0; i < 8; ++i) {
        int idx = base + t + i * 256;
        sdat[t + i * 256] = (idx < Ntot) ? cnt[idx] : 0;
    }
    __syncthreads();
    int vals[8];
    int s = 0;
#pragma unroll
    for (int j = 0; j < 8; ++j) { vals[j] = sdat[t * 8 + j]; s += vals[j]; }
    tsum[t] = s;
    __syncthreads();
    for (int off = 1; off < 256; off <<= 1) {
        int u = (t >= off) ? tsum[t - off] : 0;
        __syncthreads();
        tsum[t] += u;
        __syncthreads();
    }
    int run = bbase + tsum[t] - s;        // exclusive prefix of this chunk
#pragma unroll
    for (int j = 0; j < 8; ++j) { sdat[t * 8 + j] = run; run += vals[j]; }
    __syncthreads();
#pragma unroll
    for (int i = 0; i < 8; ++i) {
        int idx = base + t + i * 256;
        if (idx < Ntot) outp[idx] = sdat[t + i * 256];
    }
}

// =====================================================================
// MFMA GEMM, B-in-LDS / A-direct (r4 winner, FROZEN).
// Block = 64 rows x BN cols, 256 threads (4 waves).
// =====================================================================
template<int BN, bool ABF16>
__global__ __launch_bounds__(256) void gemm_mfma(
    const void* __restrict__ Avoid, int M,
    const unsigned short* __restrict__ Bt,
    const float* __restrict__ bl, const float* __restrict__ br,
    int dout, unsigned short* __restrict__ XL, unsigned short* __restrict__ XR)
{
    constexpr int LDA = 136;                       // shorts; pad 128+8
    constexpr int NT  = BN / 16;
    __shared__ __attribute__((aligned(16))) unsigned short Bs[BN * LDA];
    const int t  = threadIdx.x;
    const int m0 = blockIdx.x * 64;
    const int n0 = blockIdx.y * BN;

    const int w    = t >> 6;
    const int lane = t & 63;
    const int fr   = lane & 15;
    const int quad = lane >> 4;

    // ---- stage B (BN x 128 bf16 -> LDS), coalesced
#pragma unroll
    for (int i = 0; i < BN / 16; ++i) {
        int c  = t + i * 256;              // short8 chunks
        int n  = c >> 4;                   // 16 chunks per row
        int kc = (c & 15) * 8;
        *(short8*)(Bs + n * LDA + kc) =
            *(const short8*)(Bt + (size_t)(n0 + n) * 128 + kc);
    }

    // ---- load A fragments direct from global (overlaps B staging)
    const int arow = m0 + w * 16 + fr;     // this lane's A row
    const size_t abase = (size_t)(arow < M ? arow : 0) * 128 + quad * 8;
    short8 afr[4];
    if (ABF16) {
        const unsigned short* A = (const unsigned short*)Avoid;
#pragma unroll
        for (int kk = 0; kk < 4; ++kk)
            afr[kk] = *(const short8*)(A + abase + kk * 32);
    } else {
        const float* A = (const float*)Avoid;
#pragma unroll
        for (int kk = 0; kk < 4; ++kk) {
            float4 lo = *(const float4*)(A + abase + kk * 32);
            float4 hi = *(const float4*)(A + abase + kk * 32 + 4);
            afr[kk][0] = (short)f2bf(lo.x); afr[kk][1] = (short)f2bf(lo.y);
            afr[kk][2] = (short)f2bf(lo.z); afr[kk][3] = (short)f2bf(lo.w);
            afr[kk][4] = (short)f2bf(hi.x); afr[kk][5] = (short)f2bf(hi.y);
            afr[kk][6] = (short)f2bf(hi.z); afr[kk][7] = (short)f2bf(hi.w);
        }
    }
    __syncthreads();

    f32x4 acc[NT] = {};
    const unsigned short* bp = Bs + fr * LDA + quad * 8;
#pragma unroll
    for (int kk = 0; kk < 4; ++kk) {
#pragma unroll
        for (int j = 0; j < NT; ++j) {
            short8 bfr = *(const short8*)(bp + j * 16 * LDA + kk * 32);
            acc[j] = __builtin_amdgcn_mfma_f32_16x16x32_bf16(afr[kk], bfr, acc[j], 0, 0, 0);
        }
    }

    // ---- epilogue: +bias, bf16 stores into XL | XR
#pragma unroll
    for (int j = 0; j < NT; ++j) {
        int col = n0 + j * 16 + fr;
        float bias = (col < dout) ? bl[col] : br[col - dout];
#pragma unroll
        for (int r = 0; r < 4; ++r) {
            int row = m0 + w * 16 + quad * 4 + r;
            if (row < M) {
                unsigned short o = f2bf(acc[j][r] + bias);
                if (col < dout) XL[(size_t)row * dout + col] = o;
                else            XR[(size_t)row * dout + (col - dout)] = o;
            }
        }
    }
}

// =====================================================================
// CSR build (atomic-free two-level bucket sort, r5 winner, FROZEN).
// =====================================================================
__global__ __launch_bounds__(256) void csr_scatter(
    const int* __restrict__ src, const int* __restrict__ dst, int E, int tile,
    const int* __restrict__ hist_s, unsigned int* __restrict__ sorted)
{
    __shared__ int cur[256];
    const int t = threadIdx.x, b = blockIdx.x;
    cur[t] = hist_s[t * NBLK + b];
    __syncthreads();
    const int e0 = b * tile;
    const int e1 = min(E, e0 + tile);
    for (int e = e0 + t; e < e1; e += 256) {
        int d = dst[e];
        int pos = atomicAdd(&cur[d >> 8], 1);
        sorted[pos] = ((unsigned int)d << 16) | (unsigned int)src[e];
    }
}

__global__ __launch_bounds__(256) void csr_fine(
    const unsigned int* __restrict__ sorted, int E, int N,
    const int* __restrict__ hist_s,
    int* __restrict__ rowptr, unsigned short* __restrict__ csr_src)
{
    __shared__ int h[256];
    __shared__ int sc[256];
    const int t = threadIdx.x, d = blockIdx.x;
    const int start = hist_s[d * NBLK];
    const int end   = (d < 255) ? hist_s[(d + 1) * NBLK] : E;
    h[t] = 0;
    __syncthreads();
    for (int e = start + t; e < end; e += 256)
        atomicAdd(&h[(sorted[e] >> 16) & 0xFF], 1);
    __syncthreads();
    int v = h[t];
    sc[t] = v;
    __syncthreads();
    for (int off = 1; off < 256; off <<= 1) {
        int u = (t >= off) ? sc[t - off] : 0;
        __syncthreads();
        sc[t] += u;
        __syncthreads();
    }
    const int base = start + sc[t] - v;    // absolute exclusive prefix
    const int node = (d << 8) + t;
    if (node <= N) rowptr[node] = base;    // node==N lands on E exactly
    h[t] = base;                           // absolute cursor
    __syncthreads();
    for (int e = start + t; e < end; e += 256) {
        unsigned int it = sorted[e];
        int pos = atomicAdd(&h[(it >> 16) & 0xFF], 1);
        csr_src[pos] = (unsigned short)(it & 0xFFFFu);
    }
}

// =====================================================================
// Fused GATv2 edge phase — 8 ch/lane (16B dwordx4 gathers), all-scalar
// straight-line code (the r2-proven codegen style; NO ext-vector arrays,
// NO lambda-returned aggregates — that was r1's regression).
//   LPE = HC/8 (H=4: 16, H=1: 4); one head = 4 lanes for both -> the
//   head reduce is always dpp_sum4 (2 quad_perms) on the VALU pipe.
//   Leaky folded into the dot: leaky(s) = 0.6s + 0.4|s| exactly.
// =====================================================================
template<int H>
__global__ __launch_bounds__(256, 4) void gat_fused(
    const unsigned short* __restrict__ xl, const unsigned short* __restrict__ xr,
    const int* __restrict__ rowptr, const unsigned short* __restrict__ csr_src,
    const float* __restrict__ att, const float* __restrict__ bias,
    unsigned short* __restrict__ hout, int hstride, int N)
{
    constexpr int HC  = 32 * H;
    constexpr int LPE = HC / 8;      // lanes per edge, 8 ch each (H=4: 16, H=1: 4)
    constexpr int EPW = 64 / LPE;    // edge slots per wave (4 / 16)
    const int node = blockIdx.x * 4 + (threadIdx.x >> 6);
    if (node >= N) return;
    const int lane = threadIdx.x & 63;
    const int q    = lane % LPE;     // channel group: ch [8q, 8q+8)
    const int slot = lane / LPE;
    const int rs   = rowptr[node];
    const int re   = rowptr[node + 1];

    const unsigned short* __restrict__ xlb = xl + 8 * q;

    // xr_i for this lane's 8 channels (named scalars only)
    float xr0, xr1, xr2, xr3, xr4, xr5, xr6, xr7;
    {
        uint4 u = *(const uint4*)(xr + (size_t)node * HC + 8 * q);
        xr0 = lo16f(u.x); xr1 = hi16f(u.x);
        xr2 = lo16f(u.y); xr3 = hi16f(u.y);
        xr4 = lo16f(u.z); xr5 = hi16f(u.z);
        xr6 = lo16f(u.w); xr7 = hi16f(u.w);
    }
    // logit coefs with leaky folded, exp2 domain
    float b10, b11, b12, b13, b14, b15, b16, b17;
    float b20, b21, b22, b23, b24, b25, b26, b27;
    {
        float4 a0 = *(const float4*)(att + 8 * q);
        float4 a1 = *(const float4*)(att + 8 * q + 4);
        const float c1 = 0.5f * (1.0f + NEG_SLOPE) * LOG2E;   // 0.6*log2e
        const float c2 = 0.5f * (1.0f - NEG_SLOPE) * LOG2E;   // 0.4*log2e
        b10 = a0.x * c1; b11 = a0.y * c1; b12 = a0.z * c1; b13 = a0.w * c1;
        b14 = a1.x * c1; b15 = a1.y * c1; b16 = a1.z * c1; b17 = a1.w * c1;
        b20 = a0.x * c2; b21 = a0.y * c2; b22 = a0.z * c2; b23 = a0.w * c2;
        b24 = a1.x * c2; b25 = a1.y * c2; b26 = a1.z * c2; b27 = a1.w * c2;
    }

    float l = 0.f;
    float a0 = 0.f, a1 = 0.f, a2 = 0.f, a3 = 0.f;
    float a4 = 0.f, a5 = 0.f, a6 = 0.f, a7 = 0.f;

    // one edge: gather 8 ch, logit dot, quad head-reduce, accumulate.
    auto edge1 = [&](int s) {
        uint4 u = *(const uint4*)(xlb + (size_t)s * HC);
        float v0 = lo16f(u.x), v1 = hi16f(u.x);
        float v2 = lo16f(u.y), v3 = hi16f(u.y);
        float v4 = lo16f(u.z), v5 = hi16f(u.z);
        float v6 = lo16f(u.w), v7 = hi16f(u.w);
        float t0 = v0 + xr0, t1 = v1 + xr1, t2 = v2 + xr2, t3 = v3 + xr3;
        float t4 = v4 + xr4, t5 = v5 + xr5, t6 = v6 + xr6, t7 = v7 + xr7;
        float p  = b10 * t0;
        float pq = b20 * fabsf(t0);
        p  = fmaf(b11, t1, p);  pq = fmaf(b21, fabsf(t1), pq);
        p  = fmaf(b12, t2, p);  pq = fmaf(b22, fabsf(t2), pq);
        p  = fmaf(b13, t3, p);  pq = fmaf(b23, fabsf(t3), pq);
        p  = fmaf(b14, t4, p);  pq = fmaf(b24, fabsf(t4), pq);
        p  = fmaf(b15, t5, p);  pq = fmaf(b25, fabsf(t5), pq);
        p  = fmaf(b16, t6, p);  pq = fmaf(b26, fabsf(t6), pq);
        p  = fmaf(b17, t7, p);  pq = fmaf(b27, fabsf(t7), pq);
        p += pq;
        p = dpp_sum4(p);                 // head = 4 lanes (quad-aligned)
        float w = exp2f(p);
        l += w;
        a0 = fmaf(w, v0, a0); a1 = fmaf(w, v1, a1);
        a2 = fmaf(w, v2, a2); a3 = fmaf(w, v3, a3);
        a4 = fmaf(w, v4, a4); a5 = fmaf(w, v5, a5);
        a6 = fmaf(w, v6, a6); a7 = fmaf(w, v7, a7);
    };
    // two edges with both gathers issued up front (loads overlap).
    auto edge2 = [&](int s0, int s1) {
        uint4 u0 = *(const uint4*)(xlb + (size_t)s0 * HC);
        uint4 u1 = *(const uint4*)(xlb + (size_t)s1 * HC);
        {
            float v0 = lo16f(u0.x), v1 = hi16f(u0.x);
            float v2 = lo16f(u0.y), v3 = hi16f(u0.y);
            float v4 = lo16f(u0.z), v5 = hi16f(u0.z);
            float v6 = lo16f(u0.w), v7 = hi16f(u0.w);
            float t0 = v0 + xr0, t1 = v1 + xr1, t2 = v2 + xr2, t3 = v3 + xr3;
            float t4 = v4 + xr4, t5 = v5 + xr5, t6 = v6 + xr6, t7 = v7 + xr7;
            float p  = b10 * t0;
            float pq = b20 * fabsf(t0);
            p  = fmaf(b11, t1, p);  pq = fmaf(b21, fabsf(t1), pq);
            p  = fmaf(b12, t2, p);  pq = fmaf(b22, fabsf(t2), pq);
            p  = fmaf(b13, t3, p);  pq = fmaf(b23, fabsf(t3), pq);
            p  = fmaf(b14, t4, p);  pq = fmaf(b24, fabsf(t4), pq);
            p  = fmaf(b15, t5, p);  pq = fmaf(b25, fabsf(t5), pq);
            p  = fmaf(b16, t6, p);  pq = fmaf(b26, fabsf(t6), pq);
            p  = fmaf(b17, t7, p);  pq = fmaf(b27, fabsf(t7), pq);
            p += pq;
            p = dpp_sum4(p);
            float w = exp2f(p);
            l += w;
            a0 = fmaf(w, v0, a0); a1 = fmaf(w, v1, a1);
            a2 = fmaf(w, v2, a2); a3 = fmaf(w, v3, a3);
            a4 = fmaf(w, v4, a4); a5 = fmaf(w, v5, a5);
            a6 = fmaf(w, v6, a6); a7 = fmaf(w, v7, a7);
        }
        {
            float v0 = lo16f(u1.x), v1 = hi16f(u1.x);
            float v2 = lo16f(u1.y), v3 = hi16f(u1.y);
            float v4 = lo16f(u1.z), v5 = hi16f(u1.z);
            float v6 = lo16f(u1.w), v7 = hi16f(u1.w);
            float t0 = v0 + xr0, t1 = v1 + xr1, t2 = v2 + xr2, t3 = v3 + xr3;
            float t4 = v4 + xr4, t5 = v5 + xr5, t6 = v6 + xr6, t7 = v7 + xr7;
            float p  = b10 * t0;
            float pq = b20 * fabsf(t0);
            p  = fmaf(b11, t1, p);  pq = fmaf(b21, fabsf(t1), pq);
            p  = fmaf(b12, t2, p);  pq = fmaf(b22, fabsf(t2), pq);
            p  = fmaf(b13, t3, p);  pq = fmaf(b23, fabsf(t3), pq);
            p  = fmaf(b14, t4, p);  pq = fmaf(b24, fabsf(t4), pq);
            p  = fmaf(b15, t5, p);  pq = fmaf(b25, fabsf(t5), pq);
            p  = fmaf(b16, t6, p);  pq = fmaf(b26, fabsf(t6), pq);
            p  = fmaf(b17, t7, p);  pq = fmaf(b27, fabsf(t7), pq);
            p += pq;
            p = dpp_sum4(p);
            float w = exp2f(p);
            l += w;
            a0 = fmaf(w, v0, a0); a1 = fmaf(w, v1, a1);
            a2 = fmaf(w, v2, a2); a3 = fmaf(w, v3, a3);
            a4 = fmaf(w, v4, a4); a5 = fmaf(w, v5, a5);
            a6 = fmaf(w, v6, a6); a7 = fmaf(w, v7, a7);
        }
    };

    // ---- self-loop (src = dst = node), slot 0 only
    if (slot == 0) edge1(node);

    // ---- incoming edges, strided per slot, unrolled x2
    int k = rs + slot;
    for (; k + EPW < re; k += 2 * EPW)
        edge2(csr_src[k], csr_src[k + EPW]);
    if (k < re)
        edge1(csr_src[k]);

    // ---- merge edge slots (once per node)
#pragma unroll
    for (int mask = LPE; mask < 64; mask <<= 1) {
        l  += __shfl_xor(l, mask);
        a0 += __shfl_xor(a0, mask); a1 += __shfl_xor(a1, mask);
        a2 += __shfl_xor(a2, mask); a3 += __shfl_xor(a3, mask);
        a4 += __shfl_xor(a4, mask); a5 += __shfl_xor(a5, mask);
        a6 += __shfl_xor(a6, mask); a7 += __shfl_xor(a7, mask);
    }

    if (lane < LPE) {
        float4 bi0 = *(const float4*)(bias + 8 * q);
        float4 bi1 = *(const float4*)(bias + 8 * q + 4);
        float inv = 1.f / (l + 1e-16f);
        float o0 = a0 * inv + bi0.x, o1 = a1 * inv + bi0.y;
        float o2 = a2 * inv + bi0.z, o3 = a3 * inv + bi0.w;
        float o4 = a4 * inv + bi1.x, o5 = a5 * inv + bi1.y;
        float o6 = a6 * inv + bi1.z, o7 = a7 * inv + bi1.w;
        o0 = (o0 > 0.f) ? o0 : expm1f(o0);
        o1 = (o1 > 0.f) ? o1 : expm1f(o1);
        o2 = (o2 > 0.f) ? o2 : expm1f(o2);
        o3 = (o3 > 0.f) ? o3 : expm1f(o3);
        o4 = (o4 > 0.f) ? o4 : expm1f(o4);
        o5 = (o5 > 0.f) ? o5 : expm1f(o5);
        o6 = (o6 > 0.f) ? o6 : expm1f(o6);
        o7 = (o7 > 0.f) ? o7 : expm1f(o7);
        uint4 ob;
        ob.x = ((unsigned)f2bf(o1) << 16) | f2bf(o0);
        ob.y = ((unsigned)f2bf(o3) << 16) | f2bf(o2);
        ob.z = ((unsigned)f2bf(o5) << 16) | f2bf(o4);
        ob.w = ((unsigned)f2bf(o7) << 16) | f2bf(o6);
        *(uint4*)(hout + (size_t)node * hstride + 8 * q) = ob;
    }
}

// =====================================================================
// Fused mean-pool + MLP head (h is bf16).
// =====================================================================
__global__ __launch_bounds__(128) void pool_head_kernel(
    const unsigned short* __restrict__ h, int hstride,
    const int* __restrict__ batch, int N,
    const float* __restrict__ meta,
    const float* __restrict__ Wh1, const float* __restrict__ bh1,
    const float* __restrict__ Wh2, const float* __restrict__ bh2,
    float* __restrict__ out)
{
    const int b = blockIdx.x;
    const int t = threadIdx.x;
    __shared__ float s[128];
    __shared__ float z[44];

    int lo = 0, hi = N;
    while (lo < hi) { int mid = (lo + hi) >> 1; if (batch[mid] < b) lo = mid + 1; else hi = mid; }
    int lo2 = lo, hi2 = N;
    while (lo2 < hi2) { int mid = (lo2 + hi2) >> 1; if (batch[mid] < b + 1) lo2 = mid + 1; else hi2 = mid; }
    const int start = lo, end = lo2;

    const int c = t & 31, r = t >> 5;     // 4 rows x 32 channels in flight
    float acc = 0.f;
    for (int row = start + r; row < end; row += 4)
        acc += bf2f(h[(size_t)row * hstride + c]);
    s[t] = acc;
    __syncthreads();
    if (t < 32) {
        float sum = s[t] + s[t + 32] + s[t + 64] + s[t + 96];
        z[t] = sum / fmaxf((float)(end - start), 1.0f);
    } else if (t < 44) {
        z[t] = meta[(size_t)b * 12 + (t - 32)];
    }
    __syncthreads();
    if (t < 32) {
        float hj = bh1[t];
#pragma unroll
        for (int k = 0; k < 44; ++k)
            hj = fmaf(z[k], Wh1[k * 32 + t], hj);
        hj = fmaxf(hj, 0.f);
        float p = hj * Wh2[t];
#pragma unroll
        for (int off = 16; off >= 1; off >>= 1)
            p += __shfl_xor(p, off, 32);
        if (t == 0) out[b] = p + bh2[0];
    }
}

// =====================================================================
extern "C" void kernel_launch(void* const* d_in, const int* in_sizes, int n_in,
                              void* d_out, int out_size, void* d_ws, size_t ws_size,
                              hipStream_t stream)
{
    const float* x     = (const float*)d_in[0];
    const int*   ei    = (const int*)d_in[1];
    const int*   batch = (const int*)d_in[2];
    const float* meta  = (const float*)d_in[3];
    const float* Wl[3]  = {(const float*)d_in[4],  (const float*)d_in[10], (const float*)d_in[16]};
    const float* bl[3]  = {(const float*)d_in[5],  (const float*)d_in[11], (const float*)d_in[17]};
    const float* Wr[3]  = {(const float*)d_in[6],  (const float*)d_in[12], (const float*)d_in[18]};
    const float* br[3]  = {(const float*)d_in[7],  (const float*)d_in[13], (const float*)d_in[19]};
    const float* att[3] = {(const float*)d_in[8],  (const float*)d_in[14], (const float*)d_in[20]};
    const float* bb[3]  = {(const float*)d_in[9],  (const float*)d_in[15], (const float*)d_in[21]};
    const float* Wh1 = (const float*)d_in[22];
    const float* bh1 = (const float*)d_in[23];
    const float* Wh2 = (const float*)d_in[24];
    const float* bh2 = (const float*)d_in[25];
    float* out = (float*)d_out;

    const int N  = in_sizes[0] / 128;
    const int E  = in_sizes[1] / 2;
    const int B  = in_sizes[3] / 12;

    char* wsp = (char*)d_ws;
    size_t off_ = 0;
    auto alloc = [&](size_t bytes) {
        char* p = wsp + off_;
        off_ = (off_ + bytes + 255) & ~(size_t)255;
        return p;
    };
    unsigned short* xlbuf = (unsigned short*)alloc((size_t)N * 128 * 2);  // bf16 gather table
    unsigned short* xrbuf = (unsigned short*)alloc((size_t)N * 128 * 2);  // bf16 xr table
    unsigned short* hbuf  = (unsigned short*)alloc((size_t)N * 128 * 2);  // bf16 layer output
    int*   rowptr  = (int*)alloc((size_t)(N + 1) * 4);
    unsigned short* csr_src = (unsigned short*)alloc((size_t)E * 2);  // src < 65536
    unsigned int*   sorted  = (unsigned int*)alloc((size_t)E * 4);    // (dst<<16)|src, coarse-ordered
    int*   hist_g  = (int*)alloc((size_t)65536 * 4);                  // hist[digit][block]
    int*   hist_s  = (int*)alloc((size_t)65537 * 4);                  // scanned
    unsigned short* Bt0     = (unsigned short*)alloc((size_t)256 * 128 * 2);
    unsigned short* Bt1     = (unsigned short*)alloc((size_t)256 * 128 * 2);
    unsigned short* Bt2     = (unsigned short*)alloc((size_t)64 * 128 * 2);
    int*   bsum    = (int*)alloc((size_t)256 * 4);

    const int* srcI = ei;
    const int* dstI = ei + E;

    // ---- weight prep + CSR coarse hist (fused, one dispatch)
    const int tile = (E + NBLK - 1) / NBLK;
    prep_and_hist<<<288, 256, 0, stream>>>(
        Wl[0], Wr[0], Wl[1], Wr[1], Wl[2], Wr[2], Bt0, Bt1, Bt2,
        dstI, E, tile, hist_g);

    // ---- 2-dispatch scan of the 65536 hist
    scan_partial<<<32, 256, 0, stream>>>(hist_g, 65536, bsum);
    scan_final32<<<32, 256, 0, stream>>>(hist_g, 65536, bsum, hist_s);

    csr_scatter<<<NBLK, 256, 0, stream>>>(srcI, dstI, E, tile, hist_s, sorted);
    csr_fine<<<(N >> 8) + 1, 256, 0, stream>>>(sorted, E, N, hist_s, rowptr, csr_src);

    const int GB = (N + 3) / 4;     // gat_fused blocks (4 nodes / 256-thread block)
    const int MB = (N + 63) / 64;   // gemm row-tiles (BM=64)

    // ---- layer 0 (din=128 f32, H=4, C=32, concat)
    {
        gemm_mfma<128, false><<<dim3(MB, 2), 256, 0, stream>>>(x, N, Bt0, bl[0], br[0], 128, xlbuf, xrbuf);
        gat_fused<4><<<GB, 256, 0, stream>>>(xlbuf, xrbuf, rowptr, csr_src, att[0], bb[0], hbuf, 128, N);
    }
    // ---- layer 1 (din=128 bf16)
    {
        gemm_mfma<128, true><<<dim3(MB, 2), 256, 0, stream>>>(hbuf, N, Bt1, bl[1], br[1], 128, xlbuf, xrbuf);
        gat_fused<4><<<GB, 256, 0, stream>>>(xlbuf, xrbuf, rowptr, csr_src, att[1], bb[1], hbuf, 128, N);
    }
    // ---- layer 2 (H=1, concat=False -> mean over 1 head = identity)
    {
        gemm_mfma<64, true><<<dim3(MB, 1), 256, 0, stream>>>(hbuf, N, Bt2, bl[2], br[2], 32, xlbuf, xrbuf);
        gat_fused<1><<<GB, 256, 0, stream>>>(xlbuf, xrbuf, rowptr, csr_src, att[2], bb[2], hbuf, 32, N);
    }
    // ---- fused global mean pool + head (batch sorted -> binary search, no atomics)
    pool_head_kernel<<<B, 128, 0, stream>>>(hbuf, 32, batch, N, meta, Wh1, bh1, Wh2, bh2, out);
}

// Round 10
// 336.210 us; speedup vs baseline: 1.0549x; 1.0549x over previous
//
#include <hip/hip_runtime.h>
#include <cstdint>
#include <cstddef>

#define NEG_SLOPE 0.2f
#define LOG2E 1.44269504f
#define NBLK 256              // CSR sort: blocks in hist/scatter passes

typedef __attribute__((ext_vector_type(8))) short short8;   // 8 bf16 (4 VGPRs)
typedef __attribute__((ext_vector_type(4))) float f32x4;    // MFMA accumulator

__device__ __forceinline__ float bf2f(unsigned short u) {
    union { unsigned int i; float f; } x; x.i = ((unsigned int)u) << 16; return x.f;
}
__device__ __forceinline__ unsigned short f2bf(float f) {
    union { float f; unsigned int i; } x;
    x.f = f;
    unsigned int u = x.i;
    return (unsigned short)((u + 0x7FFFu + ((u >> 16) & 1u)) >> 16);   // RNE
}

// 8-lane sum via DPP (VALU pipe): xor1, xor2 quad_perms, row_half_mirror.
__device__ __forceinline__ float dpp_sum8(float p) {
    p += __int_as_float(__builtin_amdgcn_update_dpp(0, __float_as_int(p), 0xB1, 0xF, 0xF, true));  // quad_perm [1,0,3,2]
    p += __int_as_float(__builtin_amdgcn_update_dpp(0, __float_as_int(p), 0x4E, 0xF, 0xF, true));  // quad_perm [2,3,0,1]
    p += __int_as_float(__builtin_amdgcn_update_dpp(0, __float_as_int(p), 0x141, 0xF, 0xF, true)); // row_half_mirror
    return p;
}

// =====================================================================
// FUSED: weight prep (all 3 layers) + CSR coarse histogram (blocks<256).
// Grid = 288 blocks (prep range = 73728 elems). Proven r6/r8.
// =====================================================================
__global__ __launch_bounds__(256) void prep_and_hist(
    const float* __restrict__ Wl0, const float* __restrict__ Wr0,
    const float* __restrict__ Wl1, const float* __restrict__ Wr1,
    const float* __restrict__ Wl2, const float* __restrict__ Wr2,
    unsigned short* __restrict__ Bt0, unsigned short* __restrict__ Bt1,
    unsigned short* __restrict__ Bt2,
    const int* __restrict__ dst, int E, int tile, int* __restrict__ hist)
{
    __shared__ int h[256];
    const int t = threadIdx.x;
    const int b = blockIdx.x;
    if (b < NBLK) {                       // block-uniform branch: barriers safe
        h[t] = 0;
        __syncthreads();
        const int e0 = b * tile;
        const int e1 = min(E, e0 + tile);
        for (int e = e0 + t; e < e1; e += 256)
            atomicAdd(&h[dst[e] >> 8], 1);
        __syncthreads();
        hist[t * NBLK + b] = h[t];
    }
    // ---- weight prep
    int idx = b * 256 + t;
    const int SZ = 256 * 128;     // layer0/1 table elems
    const float *Wl, *Wr; unsigned short* Bt; int dout;
    if (idx < SZ)              { Wl = Wl0; Wr = Wr0; Bt = Bt0; dout = 128; }
    else if (idx < 2 * SZ)     { Wl = Wl1; Wr = Wr1; Bt = Bt1; dout = 128; idx -= SZ; }
    else if (idx < 2 * SZ + 64 * 128) { Wl = Wl2; Wr = Wr2; Bt = Bt2; dout = 32; idx -= 2 * SZ; }
    else return;
    int n = idx >> 7, k = idx & 127;
    float v = (n < dout) ? Wl[(size_t)k * dout + n] : Wr[(size_t)k * dout + (n - dout)];
    Bt[idx] = f2bf(v);
}

// =====================================================================
// Scan of the 65536-entry histogram in TWO dispatches (r8, frozen).
// =====================================================================
__global__ __launch_bounds__(256) void scan_partial(
    const int* __restrict__ cnt, int Ntot, int* __restrict__ bsum)
{
    __shared__ int red[4];
    const int t = threadIdx.x;
    const int base = blockIdx.x * 2048;
    int s = 0;
#pragma unroll
    for (int i = 0; i < 8; ++i) {
        int idx = base + t + i * 256;
        if (idx < Ntot) s += cnt[idx];
    }
#pragma unroll
    for (int off = 32; off >= 1; off >>= 1) s += __shfl_xor(s, off);
    if ((t & 63) == 0) red[t >> 6] = s;
    __syncthreads();
    if (t == 0) bsum[blockIdx.x] = red[0] + red[1] + red[2] + red[3];
}

__global__ __launch_bounds__(256) void scan_final32(
    const int* __restrict__ cnt, int Ntot, const int* __restrict__ bsum,
    int* __restrict__ outp)
{
    __shared__ int sdat[2048];
    __shared__ int tsum[256];
    const int t = threadIdx.x;
    const int base = blockIdx.x * 2048;
    int bbase = 0;
    for (int i = 0; i < blockIdx.x; ++i) bbase += bsum[i];   // redundant, cached
#pragma unroll
    for (int i = 0; i < 8; ++i) {
        int idx = base + t + i * 256;
        sdat[t + i * 256] = (idx < Ntot) ? cnt[idx] : 0;
    }
    __syncthreads();
    int vals[8];
    int s = 0;
#pragma unroll
    for (int j = 0; j < 8; ++j) { vals[j] = sdat[t * 8 + j]; s += vals[j]; }
    tsum[t] = s;
    __syncthreads();
    for (int off = 1; off < 256; off <<= 1) {
        int u = (t >= off) ? tsum[t - off] : 0;
        __syncthreads();
        tsum[t] += u;
        __syncthreads();
    }
    int run = bbase + tsum[t] - s;        // exclusive prefix of this chunk
#pragma unroll
    for (int j = 0; j < 8; ++j) { sdat[t * 8 + j] = run; run += vals[j]; }
    __syncthreads();
#pragma unroll
    for (int i = 0; i < 8; ++i) {
        int idx = base + t + i * 256;
        if (idx < Ntot) outp[idx] = sdat[t + i * 256];
    }
}

// =====================================================================
// MFMA GEMM, B-in-LDS / A-direct (r4 winner, FROZEN).
// Block = 64 rows x BN cols, 256 threads (4 waves).
// =====================================================================
template<int BN, bool ABF16>
__global__ __launch_bounds__(256) void gemm_mfma(
    const void* __restrict__ Avoid, int M,
    const unsigned short* __restrict__ Bt,
    const float* __restrict__ bl, const float* __restrict__ br,
    int dout, unsigned short* __restrict__ XL, unsigned short* __restrict__ XR)
{
    constexpr int LDA = 136;                       // shorts; pad 128+8
    constexpr int NT  = BN / 16;
    __shared__ __attribute__((aligned(16))) unsigned short Bs[BN * LDA];
    const int t  = threadIdx.x;
    const int m0 = blockIdx.x * 64;
    const int n0 = blockIdx.y * BN;

    const int w    = t >> 6;
    const int lane = t & 63;
    const int fr   = lane & 15;
    const int quad = lane >> 4;

    // ---- stage B (BN x 128 bf16 -> LDS), coalesced
#pragma unroll
    for (int i = 0; i < BN / 16; ++i) {
        int c  = t + i * 256;              // short8 chunks
        int n  = c >> 4;                   // 16 chunks per row
        int kc = (c & 15) * 8;
        *(short8*)(Bs + n * LDA + kc) =
            *(const short8*)(Bt + (size_t)(n0 + n) * 128 + kc);
    }

    // ---- load A fragments direct from global (overlaps B staging)
    const int arow = m0 + w * 16 + fr;     // this lane's A row
    const size_t abase = (size_t)(arow < M ? arow : 0) * 128 + quad * 8;
    short8 afr[4];
    if (ABF16) {
        const unsigned short* A = (const unsigned short*)Avoid;
#pragma unroll
        for (int kk = 0; kk < 4; ++kk)
            afr[kk] = *(const short8*)(A + abase + kk * 32);
    } else {
        const float* A = (const float*)Avoid;
#pragma unroll
        for (int kk = 0; kk < 4; ++kk) {
            float4 lo = *(const float4*)(A + abase + kk * 32);
            float4 hi = *(const float4*)(A + abase + kk * 32 + 4);
            afr[kk][0] = (short)f2bf(lo.x); afr[kk][1] = (short)f2bf(lo.y);
            afr[kk][2] = (short)f2bf(lo.z); afr[kk][3] = (short)f2bf(lo.w);
            afr[kk][4] = (short)f2bf(hi.x); afr[kk][5] = (short)f2bf(hi.y);
            afr[kk][6] = (short)f2bf(hi.z); afr[kk][7] = (short)f2bf(hi.w);
        }
    }
    __syncthreads();

    f32x4 acc[NT] = {};
    const unsigned short* bp = Bs + fr * LDA + quad * 8;
#pragma unroll
    for (int kk = 0; kk < 4; ++kk) {
#pragma unroll
        for (int j = 0; j < NT; ++j) {
            short8 bfr = *(const short8*)(bp + j * 16 * LDA + kk * 32);
            acc[j] = __builtin_amdgcn_mfma_f32_16x16x32_bf16(afr[kk], bfr, acc[j], 0, 0, 0);
        }
    }

    // ---- epilogue: +bias, bf16 stores into XL | XR
#pragma unroll
    for (int j = 0; j < NT; ++j) {
        int col = n0 + j * 16 + fr;
        float bias = (col < dout) ? bl[col] : br[col - dout];
#pragma unroll
        for (int r = 0; r < 4; ++r) {
            int row = m0 + w * 16 + quad * 4 + r;
            if (row < M) {
                unsigned short o = f2bf(acc[j][r] + bias);
                if (col < dout) XL[(size_t)row * dout + col] = o;
                else            XR[(size_t)row * dout + (col - dout)] = o;
            }
        }
    }
}

// =====================================================================
// CSR build (atomic-free two-level bucket sort, r5 winner).
// NEW in r10: csr_fine reserves one SELF-LOOP slot per node (first
// entry of each node's range = the node itself). rowptr then covers
// deg+1 edges uniformly and gat_fused loses its divergent
// slot==0 self-loop branch. csr_src is sized E+N.
// =====================================================================
__global__ __launch_bounds__(256) void csr_scatter(
    const int* __restrict__ src, const int* __restrict__ dst, int E, int tile,
    const int* __restrict__ hist_s, unsigned int* __restrict__ sorted)
{
    __shared__ int cur[256];
    const int t = threadIdx.x, b = blockIdx.x;
    cur[t] = hist_s[t * NBLK + b];
    __syncthreads();
    const int e0 = b * tile;
    const int e1 = min(E, e0 + tile);
    for (int e = e0 + t; e < e1; e += 256) {
        int d = dst[e];
        int pos = atomicAdd(&cur[d >> 8], 1);
        sorted[pos] = ((unsigned int)d << 16) | (unsigned int)src[e];
    }
}

__global__ __launch_bounds__(256) void csr_fine(
    const unsigned int* __restrict__ sorted, int E, int N,
    const int* __restrict__ hist_s,
    int* __restrict__ rowptr, unsigned short* __restrict__ csr_src)
{
    __shared__ int h[256];
    __shared__ int sc[256];
    const int t = threadIdx.x, d = blockIdx.x;
    const int start = hist_s[d * NBLK];          // edges before this bucket
    const int end   = (d < 255) ? hist_s[(d + 1) * NBLK] : E;
    const int node  = (d << 8) + t;
    const int nodes_before = d << 8;             // prior buckets are full (d*256 <= N)
    h[t] = 0;
    __syncthreads();
    for (int e = start + t; e < end; e += 256)
        atomicAdd(&h[(sorted[e] >> 16) & 0xFF], 1);
    __syncthreads();
    int v = h[t] + ((node < N) ? 1 : 0);   // +1 reserved self-loop slot
    sc[t] = v;
    __syncthreads();
    for (int off = 1; off < 256; off <<= 1) {
        int u = (t >= off) ? sc[t - off] : 0;
        __syncthreads();
        sc[t] += u;
        __syncthreads();
    }
    const int base = start + nodes_before + sc[t] - v;  // absolute exclusive prefix in csr_src'
    if (node <= N) rowptr[node] = base;    // node==N lands on E+N exactly
    h[t] = base + ((node < N) ? 1 : 0);    // cursor starts after the self-loop
    __syncthreads();
    if (node < N) csr_src[base] = (unsigned short)node;   // self-loop first
    for (int e = start + t; e < end; e += 256) {
        unsigned int it = sorted[e];
        int pos = atomicAdd(&h[(it >> 16) & 0xFF], 1);
        csr_src[pos] = (unsigned short)(it & 0xFFFFu);
    }
}

// =====================================================================
// Fused GATv2 edge phase — r8-proven body (4 ch/lane, dpp_sum8, leaky
// folded into the dot), with the self-loop now IN the CSR: no divergent
// slot==0 branch; all deg+1 edges go through the uniform strided loop.
// =====================================================================
template<int H>
__global__ __launch_bounds__(256, 4) void gat_fused(
    const unsigned short* __restrict__ xl, const unsigned short* __restrict__ xr,
    const int* __restrict__ rowptr, const unsigned short* __restrict__ csr_src,
    const float* __restrict__ att, const float* __restrict__ bias,
    unsigned short* __restrict__ hout, int hstride, int N)
{
    constexpr int HC  = 32 * H;
    constexpr int LPE = HC / 4;      // lanes per edge (H=4: 32, H=1: 8)
    constexpr int EPW = 64 / LPE;    // edge slots per wave (2 / 8)
    const int node = blockIdx.x * 4 + (threadIdx.x >> 6);
    if (node >= N) return;
    const int lane = threadIdx.x & 63;
    const int q    = lane % LPE;
    const int slot = lane / LPE;
    const int rs   = rowptr[node];
    const int re   = rowptr[node + 1];

    const unsigned short* __restrict__ xlb = xl + 4 * q;
    float4 xri;
    {
        ushort4 u = *(const ushort4*)(xr + (size_t)node * HC + 4 * q);
        xri.x = bf2f(u.x); xri.y = bf2f(u.y); xri.z = bf2f(u.z); xri.w = bf2f(u.w);
    }
    // logit coefs with leaky folded, exp2 domain
    float4 b1, b2;
    {
        float4 a = *(const float4*)(att + 4 * q);
        const float c1 = 0.5f * (1.0f + NEG_SLOPE) * LOG2E;   // 0.6*log2e
        const float c2 = 0.5f * (1.0f - NEG_SLOPE) * LOG2E;   // 0.4*log2e
        b1.x = a.x * c1; b1.y = a.y * c1; b1.z = a.z * c1; b1.w = a.w * c1;
        b2.x = a.x * c2; b2.y = a.y * c2; b2.z = a.z * c2; b2.w = a.w * c2;
    }

    float l = 0.f;
    float4 acc = make_float4(0.f, 0.f, 0.f, 0.f);

    auto ld4 = [&](int s) -> float4 {
        ushort4 u = *(const ushort4*)(xlb + (size_t)s * HC);
        float4 v;
        v.x = bf2f(u.x); v.y = bf2f(u.y); v.z = bf2f(u.z); v.w = bf2f(u.w);
        return v;
    };

    auto edge_w = [&](const float4& v) -> float {   // exp2(att . leakyrelu(v+xri))
        float sx = v.x + xri.x, sy = v.y + xri.y, sz = v.z + xri.z, sw = v.w + xri.w;
        float p  = b1.x * sx;
        float pq = b2.x * fabsf(sx);
        p  = fmaf(b1.y, sy, p);
        pq = fmaf(b2.y, fabsf(sy), pq);
        p  = fmaf(b1.z, sz, p);
        pq = fmaf(b2.z, fabsf(sz), pq);
        p  = fmaf(b1.w, sw, p);
        pq = fmaf(b2.w, fabsf(sw), pq);
        p += pq;
        p = dpp_sum8(p);                 // 8-lane head reduce, VALU pipe
        return exp2f(p);
    };

    // ---- all deg+1 edges (self-loop included in CSR), strided per slot,
    //      unrolled x2 (no predication)
    int k = rs + slot;
    for (; k + EPW < re; k += 2 * EPW) {
        int s0 = csr_src[k];
        int s1 = csr_src[k + EPW];
        float4 v0 = ld4(s0);
        float4 v1 = ld4(s1);
        float w0 = edge_w(v0);
        float w1 = edge_w(v1);
        l += w0 + w1;
        acc.x = fmaf(w0, v0.x, fmaf(w1, v1.x, acc.x));
        acc.y = fmaf(w0, v0.y, fmaf(w1, v1.y, acc.y));
        acc.z = fmaf(w0, v0.z, fmaf(w1, v1.z, acc.z));
        acc.w = fmaf(w0, v0.w, fmaf(w1, v1.w, acc.w));
    }
    if (k < re) {
        int s0 = csr_src[k];
        float4 v0 = ld4(s0);
        float w0 = edge_w(v0);
        l += w0;
        acc.x = fmaf(w0, v0.x, acc.x);
        acc.y = fmaf(w0, v0.y, acc.y);
        acc.z = fmaf(w0, v0.z, acc.z);
        acc.w = fmaf(w0, v0.w, acc.w);
    }

    // ---- merge edge slots: plain sums (once per node)
#pragma unroll
    for (int mask = LPE; mask < 64; mask <<= 1) {
        l     += __shfl_xor(l, mask);
        acc.x += __shfl_xor(acc.x, mask);
        acc.y += __shfl_xor(acc.y, mask);
        acc.z += __shfl_xor(acc.z, mask);
        acc.w += __shfl_xor(acc.w, mask);
    }

    if (lane < LPE) {
        const float4 bi = *(const float4*)(bias + 4 * q);
        float inv = 1.f / (l + 1e-16f);
        float4 o;
        o.x = acc.x * inv + bi.x;
        o.y = acc.y * inv + bi.y;
        o.z = acc.z * inv + bi.z;
        o.w = acc.w * inv + bi.w;
        o.x = (o.x > 0.f) ? o.x : expm1f(o.x);
        o.y = (o.y > 0.f) ? o.y : expm1f(o.y);
        o.z = (o.z > 0.f) ? o.z : expm1f(o.z);
        o.w = (o.w > 0.f) ? o.w : expm1f(o.w);
        ushort4 ob;
        ob.x = f2bf(o.x); ob.y = f2bf(o.y); ob.z = f2bf(o.z); ob.w = f2bf(o.w);
        *(ushort4*)(hout + (size_t)node * hstride + 4 * q) = ob;
    }
}

// =====================================================================
// Fused mean-pool + MLP head (h is bf16).
// =====================================================================
__global__ __launch_bounds__(128) void pool_head_kernel(
    const unsigned short* __restrict__ h, int hstride,
    const int* __restrict__ batch, int N,
    const float* __restrict__ meta,
    const float* __restrict__ Wh1, const float* __restrict__ bh1,
    const float* __restrict__ Wh2, const float* __restrict__ bh2,
    float* __restrict__ out)
{
    const int b = blockIdx.x;
    const int t = threadIdx.x;
    __shared__ float s[128];
    __shared__ float z[44];

    int lo = 0, hi = N;
    while (lo < hi) { int mid = (lo + hi) >> 1; if (batch[mid] < b) lo = mid + 1; else hi = mid; }
    int lo2 = lo, hi2 = N;
    while (lo2 < hi2) { int mid = (lo2 + hi2) >> 1; if (batch[mid] < b + 1) lo2 = mid + 1; else hi2 = mid; }
    const int start = lo, end = lo2;

    const int c = t & 31, r = t >> 5;     // 4 rows x 32 channels in flight
    float acc = 0.f;
    for (int row = start + r; row < end; row += 4)
        acc += bf2f(h[(size_t)row * hstride + c]);
    s[t] = acc;
    __syncthreads();
    if (t < 32) {
        float sum = s[t] + s[t + 32] + s[t + 64] + s[t + 96];
        z[t] = sum / fmaxf((float)(end - start), 1.0f);
    } else if (t < 44) {
        z[t] = meta[(size_t)b * 12 + (t - 32)];
    }
    __syncthreads();
    if (t < 32) {
        float hj = bh1[t];
#pragma unroll
        for (int k = 0; k < 44; ++k)
            hj = fmaf(z[k], Wh1[k * 32 + t], hj);
        hj = fmaxf(hj, 0.f);
        float p = hj * Wh2[t];
#pragma unroll
        for (int off = 16; off >= 1; off >>= 1)
            p += __shfl_xor(p, off, 32);
        if (t == 0) out[b] = p + bh2[0];
    }
}

// =====================================================================
extern "C" void kernel_launch(void* const* d_in, const int* in_sizes, int n_in,
                              void* d_out, int out_size, void* d_ws, size_t ws_size,
                              hipStream_t stream)
{
    const float* x     = (const float*)d_in[0];
    const int*   ei    = (const int*)d_in[1];
    const int*   batch = (const int*)d_in[2];
    const float* meta  = (const float*)d_in[3];
    const float* Wl[3]  = {(const float*)d_in[4],  (const float*)d_in[10], (const float*)d_in[16]};
    const float* bl[3]  = {(const float*)d_in[5],  (const float*)d_in[11], (const float*)d_in[17]};
    const float* Wr[3]  = {(const float*)d_in[6],  (const float*)d_in[12], (const float*)d_in[18]};
    const float* br[3]  = {(const float*)d_in[7],  (const float*)d_in[13], (const float*)d_in[19]};
    const float* att[3] = {(const float*)d_in[8],  (const float*)d_in[14], (const float*)d_in[20]};
    const float* bb[3]  = {(const float*)d_in[9],  (const float*)d_in[15], (const float*)d_in[21]};
    const float* Wh1 = (const float*)d_in[22];
    const float* bh1 = (const float*)d_in[23];
    const float* Wh2 = (const float*)d_in[24];
    const float* bh2 = (const float*)d_in[25];
    float* out = (float*)d_out;

    const int N  = in_sizes[0] / 128;
    const int E  = in_sizes[1] / 2;
    const int B  = in_sizes[3] / 12;

    char* wsp = (char*)d_ws;
    size_t off_ = 0;
    auto alloc = [&](size_t bytes) {
        char* p = wsp + off_;
        off_ = (off_ + bytes + 255) & ~(size_t)255;
        return p;
    };
    unsigned short* xlbuf = (unsigned short*)alloc((size_t)N * 128 * 2);  // bf16 gather table
    unsigned short* xrbuf = (unsigned short*)alloc((size_t)N * 128 * 2);  // bf16 xr table
    unsigned short* hbuf  = (unsigned short*)alloc((size_t)N * 128 * 2);  // bf16 layer output
    int*   rowptr  = (int*)alloc((size_t)(N + 1) * 4);
    unsigned short* csr_src = (unsigned short*)alloc((size_t)(E + N) * 2);  // +N self-loop slots
    unsigned int*   sorted  = (unsigned int*)alloc((size_t)E * 4);    // (dst<<16)|src, coarse-ordered
    int*   hist_g  = (int*)alloc((size_t)65536 * 4);                  // hist[digit][block]
    int*   hist_s  = (int*)alloc((size_t)65537 * 4);                  // scanned
    unsigned short* Bt0     = (unsigned short*)alloc((size_t)256 * 128 * 2);
    unsigned short* Bt1     = (unsigned short*)alloc((size_t)256 * 128 * 2);
    unsigned short* Bt2     = (unsigned short*)alloc((size_t)64 * 128 * 2);
    int*   bsum    = (int*)alloc((size_t)256 * 4);

    const int* srcI = ei;
    const int* dstI = ei + E;

    // ---- weight prep + CSR coarse hist (fused, one dispatch)
    const int tile = (E + NBLK - 1) / NBLK;
    prep_and_hist<<<288, 256, 0, stream>>>(
        Wl[0], Wr[0], Wl[1], Wr[1], Wl[2], Wr[2], Bt0, Bt1, Bt2,
        dstI, E, tile, hist_g);

    // ---- 2-dispatch scan of the 65536 hist
    scan_partial<<<32, 256, 0, stream>>>(hist_g, 65536, bsum);
    scan_final32<<<32, 256, 0, stream>>>(hist_g, 65536, bsum, hist_s);

    csr_scatter<<<NBLK, 256, 0, stream>>>(srcI, dstI, E, tile, hist_s, sorted);
    csr_fine<<<(N >> 8) + 1, 256, 0, stream>>>(sorted, E, N, hist_s, rowptr, csr_src);

    const int GB = (N + 3) / 4;     // gat_fused blocks (4 nodes / 256-thread block)
    const int MB = (N + 63) / 64;   // gemm row-tiles (BM=64)

    // ---- layer 0 (din=128 f32, H=4, C=32, concat)
    {
        gemm_mfma<128, false><<<dim3(MB, 2), 256, 0, stream>>>(x, N, Bt0, bl[0], br[0], 128, xlbuf, xrbuf);
        gat_fused<4><<<GB, 256, 0, stream>>>(xlbuf, xrbuf, rowptr, csr_src, att[0], bb[0], hbuf, 128, N);
    }
    // ---- layer 1 (din=128 bf16)
    {
        gemm_mfma<128, true><<<dim3(MB, 2), 256, 0, stream>>>(hbuf, N, Bt1, bl[1], br[1], 128, xlbuf, xrbuf);
        gat_fused<4><<<GB, 256, 0, stream>>>(xlbuf, xrbuf, rowptr, csr_src, att[1], bb[1], hbuf, 128, N);
    }
    // ---- layer 2 (H=1, concat=False -> mean over 1 head = identity)
    {
        gemm_mfma<64, true><<<dim3(MB, 1), 256, 0, stream>>>(hbuf, N, Bt2, bl[2], br[2], 32, xlbuf, xrbuf);
        gat_fused<1><<<GB, 256, 0, stream>>>(xlbuf, xrbuf, rowptr, csr_src, att[2], bb[2], hbuf, 32, N);
    }
    // ---- fused global mean pool + head (batch sorted -> binary search, no atomics)
    pool_head_kernel<<<B, 128, 0, stream>>>(hbuf, 32, batch, N, meta, Wh1, bh1, Wh2, bh2, out);
}